// Round 5
// baseline (170.465 us; speedup 1.0000x reference)
//
#include <hip/hip_runtime.h>
#include <hip/hip_bf16.h>
#include <cstdint>

#define N_SPK 1024
#define M_UTT 20
#define D_DIM 768
#define NM_ROWS (N_SPK * M_UTT)   // 20480 utterances / rows

static constexpr float EPS = 1e-8f;

typedef __attribute__((ext_vector_type(8))) short short8;   // 8 x bf16 (4 VGPRs)
typedef __attribute__((ext_vector_type(4))) float floatx4;  // MFMA accumulator

__device__ __forceinline__ void load16_to_lds(const void* g, void* l) {
    __builtin_amdgcn_global_load_lds(
        (const __attribute__((address_space(1))) uint32_t*)g,
        (__attribute__((address_space(3))) uint32_t*)l, 16, 0, 0);
}

__device__ __forceinline__ unsigned short bf16bits(float x) {
    __hip_bfloat16 h = __float2bfloat16(x);
    return *(unsigned short*)&h;
}

__device__ __forceinline__ float wave_sum(float v) {
    #pragma unroll
    for (int o = 32; o > 0; o >>= 1) v += __shfl_xor(v, o);
    return v;
}

// ---------------------------------------------------------------------------
// Kernel 1 (fused prep): per speaker, read emb once (float2/thread, 384 thr),
// compute centroid norm + 20 utterance norms, write bf16 Chat and Ehat
// ([m][i][d] layout) with ushort2 stores. Unchanged from R4.
// ---------------------------------------------------------------------------
__global__ __launch_bounds__(384) void prep_kernel(const float* __restrict__ emb,
                                                   __hip_bfloat16* __restrict__ ehat,
                                                   __hip_bfloat16* __restrict__ chat) {
    const int i = blockIdx.x;      // speaker
    const int t = threadIdx.x;     // 0..383
    const int wave = t >> 6, lane = t & 63;
    const float2* src = (const float2*)(emb + (size_t)i * M_UTT * D_DIM);

    float2 v[M_UTT];
    float ss[M_UTT];
    float2 cen = {0.f, 0.f};
    #pragma unroll
    for (int m = 0; m < M_UTT; ++m) {
        const float2 x = src[m * 384 + t];
        v[m] = x;
        ss[m] = x.x * x.x + x.y * x.y;
        cen.x += x.x; cen.y += x.y;
    }
    cen.x *= (1.f / M_UTT); cen.y *= (1.f / M_UTT);
    float css = cen.x * cen.x + cen.y * cen.y;

    __shared__ float red[M_UTT + 1][6];
    #pragma unroll
    for (int m = 0; m < M_UTT; ++m) {
        const float s = wave_sum(ss[m]);
        if (lane == 0) red[m][wave] = s;
    }
    {
        const float s = wave_sum(css);
        if (lane == 0) red[M_UTT][wave] = s;
    }
    __syncthreads();

    #pragma unroll
    for (int m = 0; m < M_UTT; ++m) {
        const float tot = red[m][0] + red[m][1] + red[m][2] +
                          red[m][3] + red[m][4] + red[m][5];
        const float rn = 1.0f / fmaxf(sqrtf(tot), EPS);
        ushort2 o;
        o.x = bf16bits(v[m].x * rn); o.y = bf16bits(v[m].y * rn);
        *(ushort2*)((unsigned short*)ehat + ((size_t)(m * N_SPK + i)) * D_DIM + 2 * t) = o;
    }
    {
        const float tot = red[M_UTT][0] + red[M_UTT][1] + red[M_UTT][2] +
                          red[M_UTT][3] + red[M_UTT][4] + red[M_UTT][5];
        const float rn = 1.0f / fmaxf(sqrtf(tot), EPS);
        ushort2 o;
        o.x = bf16bits(cen.x * rn); o.y = bf16bits(cen.y * rn);
        *(ushort2*)((unsigned short*)chat + (size_t)i * D_DIM + 2 * t) = o;
    }
}

// ---------------------------------------------------------------------------
// Kernel 2: fused GEMM + partial online-softmax epilogue.
// 128x64 tile, BK=32, 2 waves, 4x4 MFMA 16x16x32 per wave.
// NEW (R5): double-buffered LDS — prefetch of tile k+1 is issued BEFORE the
// compute on tile k, one barrier per iter. The barrier's vmcnt(0) drain still
// happens (m97 plateau structure) but ~250 cyc of load latency per iter now
// overlaps compute, vs zero overlap in R4's stage;barrier;compute;barrier.
// XCD swizzle + XOR LDS swizzle unchanged (FETCH ~= unique bytes, 0 conflicts).
// ---------------------------------------------------------------------------
__global__ __launch_bounds__(128) void gemm_fused_kernel(
        const __hip_bfloat16* __restrict__ ehat,
        const __hip_bfloat16* __restrict__ chat,
        const float* __restrict__ wp,
        const float* __restrict__ bp,
        float* __restrict__ Pmax,
        float* __restrict__ Psum,
        float* __restrict__ T) {
    __shared__ __hip_bfloat16 As[2][128 * 32];
    __shared__ __hip_bfloat16 Bs[2][64 * 32];
    __shared__ float red[2][64][2];

    const int t = threadIdx.x;          // 0..127
    const int lane = t & 63;
    const int wid = t >> 6;             // wave: row half 0/1
    const int c = lane & 15;
    const int quad = lane >> 4;

    const int xcd = blockIdx.x & 7;
    const int idx = blockIdx.x >> 3;        // 0..319
    const int bu  = xcd * 20 + (idx >> 4);  // 0..159
    const int bj  = idx & 15;               // 0..15
    const int m   = bu >> 3;
    const int rb  = bu & 7;
    const int u0  = bu * 128;
    const int j0  = bj * 64;

    const short* Ag = (const short*)ehat + (size_t)u0 * D_DIM;
    const short* Bg = (const short*)chat + (size_t)j0 * D_DIM;

    // per-thread staging addresses (XOR-swizzled 16B chunks), k-invariant part
    int aoff[4], aldso[4], boff[2], bldso[2];
    #pragma unroll
    for (int s = 0; s < 4; ++s) {
        const int ci  = s * 128 + t;
        const int row = ci >> 2;
        const int q   = (ci & 3) ^ ((row >> 1) & 3);
        aoff[s]  = row * D_DIM + q * 8;
        aldso[s] = ci * 8;
    }
    #pragma unroll
    for (int s = 0; s < 2; ++s) {
        const int ci  = s * 128 + t;
        const int row = ci >> 2;
        const int q   = (ci & 3) ^ ((row >> 1) & 3);
        boff[s]  = row * D_DIM + q * 8;
        bldso[s] = ci * 8;
    }

    // fragment LDS slots (16B units), loop-invariant
    int slotA[4], slotB[4];
    #pragma unroll
    for (int it = 0; it < 4; ++it) {
        const int r = wid * 64 + it * 16 + c;
        slotA[it] = (r * 4 + (quad ^ ((r >> 1) & 3))) * 8;
    }
    #pragma unroll
    for (int jt = 0; jt < 4; ++jt) {
        const int r = jt * 16 + c;
        slotB[jt] = (r * 4 + (quad ^ ((r >> 1) & 3))) * 8;
    }

    floatx4 acc[4][4] = {};

    // prologue: stage k=0 into buffer 0
    #pragma unroll
    for (int s = 0; s < 4; ++s) load16_to_lds(Ag + aoff[s], (short*)As[0] + aldso[s]);
    #pragma unroll
    for (int s = 0; s < 2; ++s) load16_to_lds(Bg + boff[s], (short*)Bs[0] + bldso[s]);
    __syncthreads();

    #pragma unroll 2
    for (int it24 = 0; it24 < 24; ++it24) {
        const int cur = it24 & 1;
        const int nxt = cur ^ 1;
        const int k0  = it24 * 32;
        if (it24 < 23) {   // prefetch next K-tile into the other buffer
            #pragma unroll
            for (int s = 0; s < 4; ++s)
                load16_to_lds(Ag + aoff[s] + k0 + 32, (short*)As[nxt] + aldso[s]);
            #pragma unroll
            for (int s = 0; s < 2; ++s)
                load16_to_lds(Bg + boff[s] + k0 + 32, (short*)Bs[nxt] + bldso[s]);
        }

        short8 af[4], bf[4];
        #pragma unroll
        for (int it = 0; it < 4; ++it)
            af[it] = *(const short8*)((const short*)As[cur] + slotA[it]);
        #pragma unroll
        for (int jt = 0; jt < 4; ++jt)
            bf[jt] = *(const short8*)((const short*)Bs[cur] + slotB[jt]);

        #pragma unroll
        for (int it = 0; it < 4; ++it)
            #pragma unroll
            for (int jt = 0; jt < 4; ++jt)
                acc[it][jt] = __builtin_amdgcn_mfma_f32_16x16x32_bf16(af[it], bf[jt], acc[it][jt], 0, 0, 0);
        __syncthreads();   // drains prefetch + guards buffer reuse
    }

    const float w = wp[0], b = bp[0];

    // per-column online-softmax partial over the wave's 64 rows
    float col_mx[4], col_sm[4];
    #pragma unroll
    for (int jt = 0; jt < 4; ++jt) {
        float mx = -1e30f;
        #pragma unroll
        for (int it = 0; it < 4; ++it)
            #pragma unroll
            for (int r = 0; r < 4; ++r)
                mx = fmaxf(mx, w * acc[it][jt][r] + b);
        float sm = 0.f;
        #pragma unroll
        for (int it = 0; it < 4; ++it)
            #pragma unroll
            for (int r = 0; r < 4; ++r)
                sm += __expf(w * acc[it][jt][r] + b - mx);
        #pragma unroll
        for (int off = 16; off <= 32; off <<= 1) {
            const float omx = __shfl_xor(mx, off);
            const float osm = __shfl_xor(sm, off);
            const float nm = fmaxf(mx, omx);
            sm = sm * __expf(mx - nm) + osm * __expf(omx - nm);
            mx = nm;
        }
        col_mx[jt] = mx;
        col_sm[jt] = sm;
    }
    if (quad == 0) {
        #pragma unroll
        for (int jt = 0; jt < 4; ++jt) {
            red[wid][jt * 16 + c][0] = col_mx[jt];
            red[wid][jt * 16 + c][1] = col_sm[jt];
        }
    }

    // target logit: row within m-slab == (m*1024+col)/20
    #pragma unroll
    for (int it = 0; it < 4; ++it) {
        #pragma unroll
        for (int jt = 0; jt < 4; ++jt) {
            const int col = j0 + jt * 16 + c;
            const int g = m * N_SPK + col;
            const int istar = g / M_UTT;
            const int rbase = rb * 128 + wid * 64 + it * 16 + quad * 4;
            #pragma unroll
            for (int r = 0; r < 4; ++r) {
                if (rbase + r == istar) T[g] = acc[it][jt][r];
            }
        }
    }

    __syncthreads();
    if (wid == 0) {   // wave 0 merges the two row-halves
        const int cc = lane;              // 0..63
        const float m0 = red[0][cc][0], s0 = red[0][cc][1];
        const float m1 = red[1][cc][0], s1 = red[1][cc][1];
        const float nm = fmaxf(m0, m1);
        const float ns = s0 * __expf(m0 - nm) + s1 * __expf(m1 - nm);
        const int col = j0 + cc;
        const int pidx = (m * 8 + rb) * N_SPK + col;
        Pmax[pidx] = nm;
        Psum[pidx] = ns;
    }
}

// ---------------------------------------------------------------------------
// Kernel 3: combine 8 row-block partials per (m,j) -> loss term; block sum;
// last-block pattern (ctr/accum zeroed via hipMemsetAsync) writes the output,
// eliminating the separate final kernel. fp32 atomic reorder error ~1e-5 vs
// 0.14 threshold.
// ---------------------------------------------------------------------------
__global__ void combine_kernel(const float* __restrict__ Pmax,
                               const float* __restrict__ Psum,
                               const float* __restrict__ T,
                               const float* __restrict__ wp,
                               const float* __restrict__ bp,
                               int* __restrict__ ctr,
                               float* __restrict__ accum,
                               float* __restrict__ out) {
    const int p = blockIdx.x * 256 + threadIdx.x;
    const int m = p >> 10;
    const int j = p & 1023;
    const float w = wp[0], b = bp[0];

    float M0 = -1e30f, S = 0.f;
    #pragma unroll
    for (int rb = 0; rb < 8; ++rb) {
        const int q = (m * 8 + rb) * N_SPK + j;
        const float pm = Pmax[q], ps = Psum[q];
        const float nm = fmaxf(M0, pm);
        S = S * __expf(M0 - nm) + ps * __expf(pm - nm);
        M0 = nm;
    }
    const float lse = M0 + __logf(S);
    const float term = (w * T[p] + b) - lse;

    __shared__ float red[256];
    red[threadIdx.x] = term;
    __syncthreads();
    for (int o = 128; o > 0; o >>= 1) {
        if (threadIdx.x < o) red[threadIdx.x] += red[threadIdx.x + o];
        __syncthreads();
    }
    if (threadIdx.x == 0) {
        atomicAdd(accum, red[0]);
        __threadfence();
        const int old = atomicAdd(ctr, 1);
        if (old == 79) {
            const float a = atomicAdd(accum, 0.0f);   // coherent read
            out[0] = -a / (float)NM_ROWS;
        }
    }
}

// ---------------------------------------------------------------------------
extern "C" void kernel_launch(void* const* d_in, const int* in_sizes, int n_in,
                              void* d_out, int out_size, void* d_ws, size_t ws_size,
                              hipStream_t stream) {
    const float* emb = (const float*)d_in[0];
    const float* wp  = (const float*)d_in[1];
    const float* bp  = (const float*)d_in[2];
    float* out = (float*)d_out;

    char* ws = (char*)d_ws;
    //   Ehat bf16 [M][N][D] : 31,457,280  @ 0
    //   Chat bf16 [N][D]    :  1,572,864  @ 31,457,280
    //   Pmax f32 [160][N]   :    655,360  @ 33,030,144
    //   Psum f32 [160][N]   :    655,360  @ 33,685,504
    //   T    f32 [M][N]     :     81,920  @ 34,340,864
    //   ctr  i32 + accum f32:          8  @ 34,422,784
    __hip_bfloat16* ehat = (__hip_bfloat16*)(ws);
    __hip_bfloat16* chat = (__hip_bfloat16*)(ws + 31457280);
    float* Pmax  = (float*)(ws + 33030144);
    float* Psum  = (float*)(ws + 33685504);
    float* T     = (float*)(ws + 34340864);
    int*   ctr   = (int*)  (ws + 34422784);
    float* accum = (float*)(ws + 34422788);

    hipMemsetAsync(ws + 34422784, 0, 8, stream);   // zero ctr + accum
    prep_kernel<<<dim3(N_SPK), dim3(384), 0, stream>>>(emb, ehat, chat);
    gemm_fused_kernel<<<dim3(160 * 16), dim3(128), 0, stream>>>(ehat, chat, wp, bp, Pmax, Psum, T);
    combine_kernel<<<dim3(80), dim3(256), 0, stream>>>(Pmax, Psum, T, wp, bp, ctr, accum, out);
}